// Round 6
// baseline (42.759 us; speedup 1.0000x reference)
//
#include <hip/hip_runtime.h>
#include <math.h>

#define NBLK 512   // k_main: 512 blocks x 256 threads = 1 thread per image

// ws layout (floats): [0..4095] partial[2048 waves][2] (sum, sumsq)

__device__ __forceinline__ float med3f(float a, float b, float c) {
  return __builtin_amdgcn_fmed3f(a, b, c);
}
__device__ __forceinline__ float min3f(float a, float b, float c) { return fminf(fminf(a, b), c); }
__device__ __forceinline__ float max3f(float a, float b, float c) { return fmaxf(fmaxf(a, b), c); }

// ---------------------------------------------------------------------------
// Fold shift + FC into W'[c] for pixel p (math validated on HW R1/R3/R4/R5).
__device__ __forceinline__ void fold_weights(int p, const float* __restrict__ fc_w,
                                             float sx, float sy, float* __restrict__ w8) {
  const int y = p >> 4, x = p & 15;
  const int dY = (sy > 1.0f) ? 2 : 1;
  const int dX = (sx > 1.0f) ? 2 : 1;
  const float wy1 = (float)dY - sy, wy0 = 1.0f - wy1;
  const float wx1 = (float)dX - sx, wx0 = 1.0f - wx1;
  const int   iys[2] = { y + dY - 1, y + dY };
  const float wys[2] = { wy1, wy0 };
  const int   jxs[2] = { x + dX - 1, x + dX };
  const float wxs[2] = { wx1, wx0 };
  #pragma unroll
  for (int c = 0; c < 8; ++c) {
    float acc = 0.0f;
    #pragma unroll
    for (int a = 0; a < 2; ++a) {
      if (iys[a] < 0 || iys[a] >= 8) continue;
      #pragma unroll
      for (int b = 0; b < 2; ++b) {
        if (jxs[b] < 0 || jxs[b] >= 16) continue;
        acc += wys[a] * wxs[b] * fc_w[c * 128 + iys[a] * 16 + jxs[b]];
      }
    }
    w8[c] = acc;
  }
}

// ---------------------------------------------------------------------------
// K1: one thread per image, barrier-free.
//  - all 32 input dwordx4 loads issued upfront (one HBM latency, covered by fold)
//  - wave-private W' in LDS (intra-wave DS ordering; no __syncthreads)
//  - medians fully in registers; dot via wave-uniform ds_read_b128 broadcasts
//  - per-wave (sum,sumsq) partials straight to global
__global__ __launch_bounds__(256, 2) void k_main(const float* __restrict__ x,
                                                 const float* __restrict__ fcw,
                                                 const float* __restrict__ xs,
                                                 const float* __restrict__ ys,
                                                 float* __restrict__ out,
                                                 float* __restrict__ partial) {
  __shared__ float wlds[4096];   // 4 waves x 1024 floats (wave-private W'[p][c])
  const int tid = threadIdx.x;
  const int w = tid >> 6, l = tid & 63;
  const int img = blockIdx.x * 256 + tid;
  const float* __restrict__ xi = x + (size_t)img * 128;

  // (a) whole image into registers — 32 loads back-to-back
  float rows[8][16];
  #pragma unroll
  for (int r = 0; r < 8; ++r)
    #pragma unroll
    for (int q = 0; q < 4; ++q)
      *(float4*)&rows[r][q * 4] = *(const float4*)&xi[r * 16 + q * 4];

  // (b) wave-private weight fold into LDS while loads fly (lane l -> pixels 2l, 2l+1)
  const float sx = xs[0] + 0.5f, sy = ys[0] + 0.5f;
  {
    float wa[8], wb[8];
    fold_weights(2 * l,     fcw, sx, sy, wa);
    fold_weights(2 * l + 1, fcw, sx, sy, wb);
    float* base = &wlds[w * 1024 + l * 16];
    *(float4*)&base[0]  = make_float4(wa[0], wa[1], wa[2], wa[3]);
    *(float4*)&base[4]  = make_float4(wa[4], wa[5], wa[6], wa[7]);
    *(float4*)&base[8]  = make_float4(wb[0], wb[1], wb[2], wb[3]);
    *(float4*)&base[12] = make_float4(wb[4], wb[5], wb[6], wb[7]);
  }
  const float* __restrict__ wv = &wlds[w * 1024];

  float acc[8];
  #pragma unroll
  for (int c = 0; c < 8; ++c) acc[c] = 0.0f;
  float ssum = 0.0f, ssq = 0.0f;

  #pragma unroll
  for (int r = 0; r < 8; ++r) {
    // vertical sort3 per column (zero rows outside [0,7])
    float lo[16], mi[16], hi[16];
    #pragma unroll
    for (int c = 0; c < 16; ++c) {
      const float a = (r == 0) ? 0.0f : rows[r - 1][c];
      const float b = rows[r][c];
      const float d = (r == 7) ? 0.0f : rows[r + 1][c];
      lo[c] = min3f(a, b, d);
      mi[c] = med3f(a, b, d);
      hi[c] = max3f(a, b, d);
    }
    // horizontal combine (zero cols outside [0,15]) + stats + dot
    #pragma unroll
    for (int j = 0; j < 16; ++j) {
      const float l0 = (j == 0) ? 0.0f : lo[j - 1];
      const float l2 = (j == 15) ? 0.0f : lo[j + 1];
      const float m0 = (j == 0) ? 0.0f : mi[j - 1];
      const float m2 = (j == 15) ? 0.0f : mi[j + 1];
      const float h0 = (j == 0) ? 0.0f : hi[j - 1];
      const float h2 = (j == 15) ? 0.0f : hi[j + 1];
      const float mx = max3f(l0, lo[j], l2);
      const float md = med3f(m0, mi[j], m2);
      const float mn = min3f(h0, hi[j], h2);
      const float med = med3f(mx, md, mn);  // exact lower-median of 9
      ssum += med;
      ssq = fmaf(med, med, ssq);
      const float4 w0 = *(const float4*)&wv[(r * 16 + j) * 8];      // broadcast
      const float4 w1 = *(const float4*)&wv[(r * 16 + j) * 8 + 4];  // broadcast
      acc[0] = fmaf(med, w0.x, acc[0]);
      acc[1] = fmaf(med, w0.y, acc[1]);
      acc[2] = fmaf(med, w0.z, acc[2]);
      acc[3] = fmaf(med, w0.w, acc[3]);
      acc[4] = fmaf(med, w1.x, acc[4]);
      acc[5] = fmaf(med, w1.y, acc[5]);
      acc[6] = fmaf(med, w1.z, acc[6]);
      acc[7] = fmaf(med, w1.w, acc[7]);
    }
  }

  // raw dots to out (scaled in k_scale)
  float4* o4 = (float4*)&out[(size_t)img * 8];
  o4[0] = make_float4(acc[0], acc[1], acc[2], acc[3]);
  o4[1] = make_float4(acc[4], acc[5], acc[6], acc[7]);

  // per-wave stats straight to global (no block reduce, no barrier)
  #pragma unroll
  for (int off = 32; off; off >>= 1) {
    ssum += __shfl_xor(ssum, off, 64);
    ssq  += __shfl_xor(ssq,  off, 64);
  }
  if (l == 0) {
    const int wg = blockIdx.x * 4 + w;
    partial[2 * wg]     = ssum;
    partial[2 * wg + 1] = ssq;
  }
}

// ---------------------------------------------------------------------------
// K2: each of 256 blocks redundantly reduces partial[4096] (L2-hot),
// recomputes the W' fold for per-class sums, then scales 4 float4 per thread:
// out = alpha*dot + (beta*wsum[c] + fcb[c]).
__global__ __launch_bounds__(256) void k_scale(float* __restrict__ out,
                                               const float* __restrict__ partial,
                                               const float* __restrict__ fcw,
                                               const float* __restrict__ xs,
                                               const float* __restrict__ ys,
                                               const float* __restrict__ fcb,
                                               const float* __restrict__ bnw,
                                               const float* __restrict__ bnb) {
  __shared__ float sred[8];
  __shared__ float wred[4][8];
  __shared__ float fin[2];
  const int tid = threadIdx.x;
  const int w = tid >> 6, l = tid & 63;

  // batch stats: 2048 wave-pairs / 256 threads = 8 each
  float s = 0.0f, q = 0.0f;
  #pragma unroll
  for (int k = 0; k < 8; ++k) {
    const int idx = tid + 256 * k;
    s += partial[2 * idx];
    q += partial[2 * idx + 1];
  }
  #pragma unroll
  for (int off = 32; off; off >>= 1) {
    s += __shfl_xor(s, off, 64);
    q += __shfl_xor(q, off, 64);
  }

  // redundant W' fold for per-class sums (threads 0..127 contribute)
  float v[8];
  if (tid < 128) {
    fold_weights(tid, fcw, xs[0] + 0.5f, ys[0] + 0.5f, v);
  } else {
    #pragma unroll
    for (int c = 0; c < 8; ++c) v[c] = 0.0f;
  }
  #pragma unroll
  for (int c = 0; c < 8; ++c) {
    #pragma unroll
    for (int off = 32; off; off >>= 1) v[c] += __shfl_xor(v[c], off, 64);
  }

  if (l == 0) {
    sred[w] = s; sred[4 + w] = q;
    #pragma unroll
    for (int c = 0; c < 8; ++c) wred[w][c] = v[c];
  }
  __syncthreads();
  if (tid == 0) {
    const float S = (sred[0] + sred[1]) + (sred[2] + sred[3]);
    const float Q = (sred[4] + sred[5]) + (sred[6] + sred[7]);
    const float N = 16777216.0f;  // 131072*128
    const float mm = S / N;
    const float vv = Q / N - mm * mm;
    const float a = bnw[0] / sqrtf(vv + 1e-5f);
    fin[0] = a;
    fin[1] = bnb[0] - mm * a;
  }
  __syncthreads();
  const float alpha = fin[0], beta = fin[1];

  // per-class constant, both halves
  float cv[8];
  #pragma unroll
  for (int c = 0; c < 8; ++c) {
    const float wsum = (wred[0][c] + wred[1][c]) + (wred[2][c] + wred[3][c]);
    cv[c] = fmaf(beta, wsum, fcb[c]);
  }
  const float4 cv0 = make_float4(cv[0], cv[1], cv[2], cv[3]);
  const float4 cv1 = make_float4(cv[4], cv[5], cv[6], cv[7]);

  float4* o4 = (float4*)out;
  const int base = (blockIdx.x * 256 + tid) * 4;  // 4 float4 per thread
  #pragma unroll
  for (int k = 0; k < 4; ++k) {
    const int i = base + k;
    const float4 c = (i & 1) ? cv1 : cv0;
    float4 ov = o4[i];
    ov.x = fmaf(alpha, ov.x, c.x);
    ov.y = fmaf(alpha, ov.y, c.y);
    ov.z = fmaf(alpha, ov.z, c.z);
    ov.w = fmaf(alpha, ov.w, c.w);
    o4[i] = ov;
  }
}

// ---------------------------------------------------------------------------
extern "C" void kernel_launch(void* const* d_in, const int* in_sizes, int n_in,
                              void* d_out, int out_size, void* d_ws, size_t ws_size,
                              hipStream_t stream) {
  const float* x   = (const float*)d_in[0];
  const float* bnw = (const float*)d_in[1];
  const float* bnb = (const float*)d_in[2];
  const float* xs  = (const float*)d_in[3];
  const float* ys  = (const float*)d_in[4];
  const float* fcw = (const float*)d_in[5];
  const float* fcb = (const float*)d_in[6];
  float* out = (float*)d_out;
  float* ws  = (float*)d_ws;

  float* partial = ws;  // 4096 floats

  hipLaunchKernelGGL(k_main,  dim3(NBLK), dim3(256), 0, stream, x, fcw, xs, ys, out, partial);
  hipLaunchKernelGGL(k_scale, dim3(256),  dim3(256), 0, stream, out, partial, fcw, xs, ys, fcb, bnw, bnb);
}